// Round 20
// baseline (649.928 us; speedup 1.0000x reference)
//
#include <hip/hip_runtime.h>

typedef unsigned short ushort_t;
typedef __attribute__((ext_vector_type(8))) short short8;
typedef __attribute__((ext_vector_type(4))) float f32x4;
typedef __attribute__((ext_vector_type(16))) float f32x16;

#define AS1U(p) ((const __attribute__((address_space(1))) unsigned int*)(p))
#define AS3U(p) ((__attribute__((address_space(3))) unsigned int*)(p))

__device__ __forceinline__ float bf2f(ushort_t u) {
  union { unsigned int i; float f; } v; v.i = ((unsigned int)u) << 16; return v.f;
}
__device__ __forceinline__ ushort_t f2bf(float f) {
  union { float f; unsigned int i; } v; v.f = f;
  unsigned int r = v.i + 0x7fffu + ((v.i >> 16) & 1u);
  return (ushort_t)(r >> 16);
}

template <int N>
__device__ __forceinline__ void waitvm() {
  if constexpr (N == 0) asm volatile("s_waitcnt vmcnt(0)" ::: "memory");
  else if constexpr (N == 2) asm volatile("s_waitcnt vmcnt(2)" ::: "memory");
  else if constexpr (N == 4) asm volatile("s_waitcnt vmcnt(4)" ::: "memory");
  else if constexpr (N == 5) asm volatile("s_waitcnt vmcnt(5)" ::: "memory");
  else if constexpr (N == 8) asm volatile("s_waitcnt vmcnt(8)" ::: "memory");
  else if constexpr (N == 10) asm volatile("s_waitcnt vmcnt(10)" ::: "memory");
}

// pack 8 f32 (S[base..base+7]) into short8 of bf16 via cvt_pk
#define PACK8(dst, S, base)                                                             \
  {                                                                                     \
    union { unsigned int u[4]; short8 s; } pk;                                          \
    asm("v_cvt_pk_bf16_f32 %0, %1, %2" : "=v"(pk.u[0]) : "v"(S[base + 0]), "v"(S[base + 1])); \
    asm("v_cvt_pk_bf16_f32 %0, %1, %2" : "=v"(pk.u[1]) : "v"(S[base + 2]), "v"(S[base + 3])); \
    asm("v_cvt_pk_bf16_f32 %0, %1, %2" : "=v"(pk.u[2]) : "v"(S[base + 4]), "v"(S[base + 5])); \
    asm("v_cvt_pk_bf16_f32 %0, %1, %2" : "=v"(pk.u[3]) : "v"(S[base + 6]), "v"(S[base + 7])); \
    dst = pk.s;                                                                         \
  }

// -------------------- f32 -> bf16, single launch over 4 segments --------------------
__global__ void cvt_all(const float* __restrict__ x, const float* __restrict__ wq,
                        const float* __restrict__ wk, const float* __restrict__ wv,
                        ushort_t* __restrict__ xb, ushort_t* __restrict__ Wb) {
  int i = blockIdx.x * 256 + threadIdx.x;
  const float* src;
  ushort_t* dst;
  int idx;
  if (i < 1310720) { src = x; dst = xb; idx = i; }
  else if (i < 6553600) { src = wq; dst = Wb; idx = i - 1310720; }
  else if (i < 7208960) { src = wk; dst = Wb + 41943040; idx = i - 6553600; }
  else { src = wv; dst = Wb + 47185920; idx = i - 7208960; }
  const float4* s4 = (const float4*)(src + (size_t)idx * 8);
  float4 a = s4[0], b = s4[1];
  short8 u;
  u[0] = (short)f2bf(a.x); u[1] = (short)f2bf(a.y); u[2] = (short)f2bf(a.z); u[3] = (short)f2bf(a.w);
  u[4] = (short)f2bf(b.x); u[5] = (short)f2bf(b.y); u[6] = (short)f2bf(b.z); u[7] = (short)f2bf(b.w);
  *(short8*)(dst + (size_t)idx * 8) = u;
}

// -------------------- f32 -> bf16 (8 elems/thread) --------------------
__global__ void cvt_bf16(const float* __restrict__ src, ushort_t* __restrict__ dst, int n8) {
  int i = blockIdx.x * 256 + threadIdx.x;
  if (i >= n8) return;
  const float4* s4 = (const float4*)src;
  float4 a = s4[2 * i], b = s4[2 * i + 1];
  short8 u;
  u[0] = (short)f2bf(a.x); u[1] = (short)f2bf(a.y); u[2] = (short)f2bf(a.z); u[3] = (short)f2bf(a.w);
  u[4] = (short)f2bf(b.x); u[5] = (short)f2bf(b.y); u[6] = (short)f2bf(b.z); u[7] = (short)f2bf(b.w);
  *(short8*)(dst + (size_t)i * 8) = u;
}

// -------------------- bf16 GEMM (pairs, ring-5, ONE barrier/pair) ---------------------
// Ring-5 makes both stage targets (b+3, b+4 mod 5) disjoint from this pair's read
// buffers (b, b+1), so the mid barrier is removable: prev boundary vmcnt(L) retires
// BOTH sub-tiles the next pair reads. One s_barrier per 64-K. BM=128 tiles (143 KB).
// gridDim.x must be a power of two; gridDim.x*gridDim.y must be a multiple of 8.
template <int OUTF32, int MF, int NF>
__global__ __launch_bounds__(512, 2) void gemmR(const ushort_t* __restrict__ A,
                                                const ushort_t* __restrict__ B,
                                                void* __restrict__ Cv,
                                                int M, int N, int K) {
  constexpr int BM = MF * 32, BN = NF * 64;
  constexpr int LA = BM / 64, LB = BN / 64;
  constexpr int LMAX = (LA > LB) ? LA : LB;
  constexpr int ABUF = BM * 32;
  __shared__ __align__(16) ushort_t SH[5][(BM + BN) * 32];
  const int t = threadIdx.x;
  const int lane = t & 63, w = t >> 6;
  const int wm = w >> 2, wn = w & 3;
  const int r = lane & 15, g = lane >> 4;
  const int nwg = gridDim.x * gridDim.y;
  const int l = blockIdx.y * gridDim.x + blockIdx.x;
  const int wg = (l & 7) * (nwg >> 3) + (l >> 3);
  const int m0 = (wg & (gridDim.x - 1)) * BM, n0 = (wg / gridDim.x) * BN;
  const int NT = K >> 5;
  const int t256 = t & 255;

  const ushort_t* sp[LMAX];
  int sdst[LMAX];
  if (w < 4) {
#pragma unroll
    for (int i = 0; i < LA; ++i) {
      int s = t256 + i * 256;
      int row = s >> 2, c = s & 3;
      int csrc = c ^ ((row >> 1) & 3);
      sp[i] = A + (size_t)(m0 + row) * K + csrc * 8;
      sdst[i] = s * 8;
    }
  } else {
#pragma unroll
    for (int i = 0; i < LB; ++i) {
      int s = t256 + i * 256;
      int row = s >> 2, c = s & 3;
      int csrc = c ^ ((row >> 1) & 3);
      sp[i] = B + (size_t)(n0 + row) * K + csrc * 8;
      sdst[i] = ABUF + s * 8;
    }
  }
  auto STAGE = [&](int b) {
    if (w < 4) {
#pragma unroll
      for (int i = 0; i < LA; ++i) {
        __builtin_amdgcn_global_load_lds(AS1U(sp[i]), AS3U(&SH[b][0] + sdst[i]), 16, 0, 0);
        sp[i] += 32;
      }
    } else {
#pragma unroll
      for (int i = 0; i < LB; ++i) {
        __builtin_amdgcn_global_load_lds(AS1U(sp[i]), AS3U(&SH[b][0] + sdst[i]), 16, 0, 0);
        sp[i] += 32;
      }
    }
  };

  // prologue: s0,s1,s2 staged; vmcnt(L) retires s0,s1 (s2 stays in flight)
  STAGE(0); STAGE(1); STAGE(2);
  if (w < 4) waitvm<LA>(); else waitvm<LB>();
  __builtin_amdgcn_s_barrier();

  f32x4 acc[MF][NF] = {};
  int bsel = 0;
  const int NI = NT >> 1;
  for (int ii = 0; ii < NI; ++ii) {
    const int s3 = 2 * ii + 3, s4 = 2 * ii + 4;
    int b1 = bsel + 1; if (b1 >= 5) b1 -= 5;
    int b3 = bsel + 3; if (b3 >= 5) b3 -= 5;
    int b4 = bsel + 4; if (b4 >= 5) b4 -= 5;
    const ushort_t* As0 = &SH[bsel][0];
    const ushort_t* Bs0 = &SH[bsel][ABUF];
    const ushort_t* As1 = &SH[b1][0];
    const ushort_t* Bs1 = &SH[b1][ABUF];
    short8 bf[NF], af0[MF / 2], af1[MF / 2];

    // ---- ph0: sub-tile 2j (A half0 + B); stage s_{2j+3} into b3 ----
#pragma unroll
    for (int m = 0; m < MF / 2; ++m) {
      int row = wm * (MF * 16) + m * 16 + r;
      af0[m] = *(const short8*)(As0 + row * 32 + (g ^ ((row >> 1) & 3)) * 8);
    }
#pragma unroll
    for (int n = 0; n < NF; ++n) {
      int row = wn * (NF * 16) + n * 16 + r;
      bf[n] = *(const short8*)(Bs0 + row * 32 + (g ^ ((row >> 1) & 3)) * 8);
    }
    if (s3 < NT) STAGE(b3);
    __builtin_amdgcn_s_setprio(1);
#pragma unroll
    for (int m = 0; m < MF / 2; ++m)
#pragma unroll
      for (int n = 0; n < NF; ++n)
        acc[m][n] = __builtin_amdgcn_mfma_f32_16x16x32_bf16(af0[m], bf[n], acc[m][n], 0, 0, 0);
    __builtin_amdgcn_s_setprio(0);

    // ---- ph1: sub-tile 2j A half1 ----
#pragma unroll
    for (int m = 0; m < MF / 2; ++m) {
      int row = wm * (MF * 16) + (MF / 2 + m) * 16 + r;
      af1[m] = *(const short8*)(As0 + row * 32 + (g ^ ((row >> 1) & 3)) * 8);
    }
    __builtin_amdgcn_s_setprio(1);
#pragma unroll
    for (int m = 0; m < MF / 2; ++m)
#pragma unroll
      for (int n = 0; n < NF; ++n)
        acc[MF / 2 + m][n] = __builtin_amdgcn_mfma_f32_16x16x32_bf16(af1[m], bf[n], acc[MF / 2 + m][n], 0, 0, 0);
    __builtin_amdgcn_s_setprio(0);

    // ---- ph2: sub-tile 2j+1 (A half0 + B); stage s_{2j+4} into b4 ----
    // (s_{2j+1} retired by PREVIOUS boundary vmcnt; no mid wait/barrier needed)
#pragma unroll
    for (int m = 0; m < MF / 2; ++m) {
      int row = wm * (MF * 16) + m * 16 + r;
      af0[m] = *(const short8*)(As1 + row * 32 + (g ^ ((row >> 1) & 3)) * 8);
    }
#pragma unroll
    for (int n = 0; n < NF; ++n) {
      int row = wn * (NF * 16) + n * 16 + r;
      bf[n] = *(const short8*)(Bs1 + row * 32 + (g ^ ((row >> 1) & 3)) * 8);
    }
    if (s4 < NT) STAGE(b4);
    __builtin_amdgcn_s_setprio(1);
#pragma unroll
    for (int m = 0; m < MF / 2; ++m)
#pragma unroll
      for (int n = 0; n < NF; ++n)
        acc[m][n] = __builtin_amdgcn_mfma_f32_16x16x32_bf16(af0[m], bf[n], acc[m][n], 0, 0, 0);
    __builtin_amdgcn_s_setprio(0);

    // ---- ph3: sub-tile 2j+1 A half1 ----
#pragma unroll
    for (int m = 0; m < MF / 2; ++m) {
      int row = wm * (MF * 16) + (MF / 2 + m) * 16 + r;
      af1[m] = *(const short8*)(As1 + row * 32 + (g ^ ((row >> 1) & 3)) * 8);
    }
    __builtin_amdgcn_s_setprio(1);
#pragma unroll
    for (int m = 0; m < MF / 2; ++m)
#pragma unroll
      for (int n = 0; n < NF; ++n)
        acc[MF / 2 + m][n] = __builtin_amdgcn_mfma_f32_16x16x32_bf16(af1[m], bf[n], acc[MF / 2 + m][n], 0, 0, 0);
    __builtin_amdgcn_s_setprio(0);

    // ---- boundary: retire s_{2j+2} AND s_{2j+3}; s_{2j+4} stays in flight ----
    if (s4 < NT) {
      if (w < 4) waitvm<LA>(); else waitvm<LB>();
    } else {
      waitvm<0>();
    }
    __builtin_amdgcn_s_barrier();
    bsel += 2; if (bsel >= 5) bsel -= 5;
  }

#pragma unroll
  for (int m = 0; m < MF; ++m)
#pragma unroll
    for (int n = 0; n < NF; ++n)
#pragma unroll
      for (int j = 0; j < 4; ++j) {
        int row = m0 + wm * (MF * 16) + m * 16 + g * 4 + j;
        int col = n0 + wn * (NF * 16) + n * 16 + r;
        if (OUTF32)
          ((float*)Cv)[(size_t)row * N + col] = acc[m][n][j];
        else
          ((ushort_t*)Cv)[(size_t)row * N + col] = f2bf(acc[m][n][j]);
      }
}

// -------------------- fused RMSNorm + RoPE + head split --------------------
__global__ __launch_bounds__(256) void normrope(const ushort_t* __restrict__ qkv,
                                                const float* __restrict__ qw, const float* __restrict__ kw,
                                                const float* __restrict__ fc, const float* __restrict__ fs,
                                                ushort_t* __restrict__ Qb, ushort_t* __restrict__ Kb) {
  const int slot = blockIdx.x * 4 + (threadIdx.x >> 6);
  const int s = blockIdx.y, t = threadIdx.x & 63;
  const ushort_t* src;
  ushort_t* dst;
  const float* wn;
  float scale = 1.0f;
  if (slot < 64) {
    src = qkv + (size_t)s * 10240 + slot * 128;
    dst = Qb + ((size_t)slot * 2048 + s) * 128;
    wn = qw;
    scale = 0.08838834764831845f;  // 1/sqrt(128) folded into Q
  } else {
    int kh = slot - 64;
    src = qkv + (size_t)s * 10240 + 8192 + kh * 128;
    dst = Kb + ((size_t)kh * 2048 + s) * 128;
    wn = kw;
  }
  float e0 = bf2f(src[2 * t]), e1 = bf2f(src[2 * t + 1]);
  float ss = e0 * e0 + e1 * e1;
#pragma unroll
  for (int m = 1; m < 64; m <<= 1) ss += __shfl_xor(ss, m);
  float rn = rsqrtf(ss * (1.0f / 128.0f) + 1e-6f);
  float v0 = e0 * rn * wn[2 * t], v1 = e1 * rn * wn[2 * t + 1];
  float c = fc[s * 64 + t], sn = fs[s * 64 + t];
  float oe = v0 * c - v1 * sn;
  float oo = v0 * sn + v1 * c;
  dst[2 * t] = f2bf(oe * scale);
  dst[2 * t + 1] = f2bf(oo * scale);
}

// -------------------- V transpose: qkv V-section [s][kvh*128+d] -> Vt[kvh][d][s] --------------------
__global__ __launch_bounds__(256) void vtrans(const ushort_t* __restrict__ qkv,
                                              ushort_t* __restrict__ Vt) {
  __shared__ __align__(16) ushort_t T[64 * 128];
  const int t = threadIdx.x, st = blockIdx.x, kvh = blockIdx.y;
#pragma unroll
  for (int i = 0; i < 4; ++i) {
    int slot = t + i * 256;
    int srow = slot >> 4, c8 = slot & 15;
    short8 v = *(const short8*)(qkv + (size_t)(st * 64 + srow) * 10240 + 9216 + kvh * 128 + c8 * 8);
    int sw = (((srow & 7) ^ ((srow >> 3) & 7)) << 4);
    *(short8*)((char*)T + srow * 256 + ((c8 * 16) ^ sw)) = v;
  }
  __syncthreads();
#pragma unroll
  for (int i = 0; i < 4; ++i) {
    int slot = t + i * 256;
    int d = slot >> 3, s8 = slot & 7;
    short8 u;
#pragma unroll
    for (int j = 0; j < 8; ++j) {
      int row = s8 * 8 + j;
      int sw = (((row & 7) ^ ((row >> 3) & 7)) << 4);
      u[j] = *(const ushort_t*)((char*)T + row * 256 + ((d * 2) ^ sw));
    }
    *(short8*)(Vt + ((size_t)kvh * 128 + d) * 2048 + st * 64 + s8 * 8) = u;
  }
}

// -------------------- causal flash attention (GQA 8:1), swapped-QK^T 32x32 --------------------
// grid 1024 linear; block remap lb -> (kvh=lb&7, hsub=(lb>>3)&7, qt=15-(lb>>6)):
// all 8 q-heads of one KV head land on ONE XCD (KV 1MB << 4MB L2), heavy qt first.
__global__ __launch_bounds__(256) void attn_fwd(const ushort_t* __restrict__ Qg,
                                                const ushort_t* __restrict__ Kg,
                                                const ushort_t* __restrict__ VtG,
                                                ushort_t* __restrict__ Og) {
  __shared__ __align__(16) ushort_t Ks[2][64 * 128];   // [kv][d], chunk-XOR swizzled
  __shared__ __align__(16) ushort_t Vs[2][128 * 64];   // [d][kv], chunk-XOR swizzled
  const int t = threadIdx.x, lane = t & 63, w = t >> 6;
  const int q5 = lane & 31, hi = lane >> 5;
  const int lb = blockIdx.x;
  const int kvh = lb & 7;
  const int h = kvh * 8 + ((lb >> 3) & 7);
  const int qt = 15 - (lb >> 6);
  const int qrow0 = qt * 128 + w * 32;
  const int qglob = qrow0 + q5;

  // permuted K row for the S^T A-operand: m = q5 -> kr = g(m)
  const int pa = q5 & 3, pp = (q5 >> 2) & 1, pb = q5 >> 3;
  const int kr = (pb >> 1) * 16 + pp * 8 + (pb & 1) * 4 + pa;
  const int kswz = (kr & 7) << 4;
  const int swz = (q5 & 7) << 4;

  // Q fragments (B-operand): col q = q5, k-slice = hi*8; 8 k-steps of 16
  short8 qf[8];
#pragma unroll
  for (int ks = 0; ks < 8; ++ks)
    qf[ks] = *(const short8*)(Qg + ((size_t)h * 2048 + qglob) * 128 + ks * 16 + hi * 8);

  f32x16 o[4] = {};
  float mrun = -3.0e38f, lrun = 0.0f;

  const int kbmax_blk = 2 * qt + 1;
  const int kbmax_w = (qrow0 + 31) >> 6;

  auto STAGE = [&](int b, int kb) {
#pragma unroll
    for (int i = 0; i < 4; ++i) {
      int slot = t + i * 256;                    // 1024 16B slots (K)
      int kv = slot >> 4, c = slot & 15;
      int csrc = c ^ (kv & 7);
      __builtin_amdgcn_global_load_lds(AS1U(Kg + ((size_t)kvh * 2048 + kb * 64 + kv) * 128 + csrc * 8),
                                       AS3U(&Ks[b][0] + slot * 8), 16, 0, 0);
    }
#pragma unroll
    for (int i = 0; i < 4; ++i) {
      int slot = t + i * 256;                    // 1024 16B slots (V^T)
      int d = slot >> 3, c = slot & 7;
      int csrc = c ^ (d & 7);
      __builtin_amdgcn_global_load_lds(AS1U(VtG + ((size_t)kvh * 128 + d) * 2048 + kb * 64 + csrc * 8),
                                       AS3U(&Vs[b][0] + slot * 8), 16, 0, 0);
    }
  };

  STAGE(0, 0);
  int cur = 0;

  for (int kb = 0; kb <= kbmax_blk; ++kb) {
    asm volatile("s_waitcnt vmcnt(0)" ::: "memory");
    __syncthreads();
    if (kb < kbmax_blk) STAGE(cur ^ 1, kb + 1);

    if (kb <= kbmax_w) {
      const char* kbase = (const char*)&Ks[cur][0];
      const char* vbase = (const char*)&Vs[cur][0];

      // ---- S^T = K_perm · Q^T ----
      f32x16 st0 = {}, st1 = {};
#pragma unroll
      for (int ks = 0; ks < 8; ++ks) {
        int cslot = ((ks * 2 + hi) * 16) ^ kswz;
        short8 kf0 = *(const short8*)(kbase + kr * 256 + cslot);
        short8 kf1 = *(const short8*)(kbase + (32 + kr) * 256 + cslot);
        __builtin_amdgcn_s_setprio(1);
        st0 = __builtin_amdgcn_mfma_f32_32x32x16_bf16(kf0, qf[ks], st0, 0, 0, 0);
        st1 = __builtin_amdgcn_mfma_f32_32x32x16_bf16(kf1, qf[ks], st1, 0, 0, 0);
        __builtin_amdgcn_s_setprio(0);
      }

      if (kb == kbmax_w) {
#pragma unroll
        for (int r = 0; r < 16; ++r) {
          int kv0 = kb * 64 + (r >> 3) * 16 + hi * 8 + (r & 7);
          if (kv0 > qglob) st0[r] = -1.0e30f;
          if (kv0 + 32 > qglob) st1[r] = -1.0e30f;
        }
      }

      float pmax = st0[0];
#pragma unroll
      for (int r = 1; r < 16; ++r) pmax = fmaxf(pmax, st0[r]);
#pragma unroll
      for (int r = 0; r < 16; ++r) pmax = fmaxf(pmax, st1[r]);
      pmax = fmaxf(pmax, __shfl_xor(pmax, 32));
      if (!__all(pmax <= mrun + 8.0f)) {
        float mn = fmaxf(mrun, pmax);
        float sc = __expf(mrun - mn);
        mrun = mn;
        lrun *= sc;
#pragma unroll
        for (int db = 0; db < 4; ++db) o[db] *= sc;
      }
      float rs = 0.0f;
#pragma unroll
      for (int r = 0; r < 16; ++r) { st0[r] = __expf(st0[r] - mrun); rs += st0[r]; }
#pragma unroll
      for (int r = 0; r < 16; ++r) { st1[r] = __expf(st1[r] - mrun); rs += st1[r]; }
      rs += __shfl_xor(rs, 32);
      lrun += rs;

      short8 pf[4];
      PACK8(pf[0], st0, 0);
      PACK8(pf[1], st0, 8);
      PACK8(pf[2], st1, 0);
      PACK8(pf[3], st1, 8);

#pragma unroll
      for (int db = 0; db < 4; ++db) {
#pragma unroll
        for (int ks = 0; ks < 4; ++ks) {
          short8 vf = *(const short8*)(vbase + (db * 32 + q5) * 128 + ((((ks * 2 + hi) * 16)) ^ swz));
          __builtin_amdgcn_s_setprio(1);
          o[db] = __builtin_amdgcn_mfma_f32_32x32x16_bf16(vf, pf[ks], o[db], 0, 0, 0);
          __builtin_amdgcn_s_setprio(0);
        }
      }
    }
    cur ^= 1;
  }

  // ---- epilogue: normalize, transpose via LDS, coalesced store ----
  __syncthreads();
  char* tr = ((char*)Ks) + w * 8192;
  float inv = 1.0f / lrun;
#pragma unroll
  for (int db = 0; db < 4; ++db)
#pragma unroll
    for (int r = 0; r < 16; r += 2) {
      unsigned int u;
      float lo = o[db][r] * inv, hiv = o[db][r + 1] * inv;
      asm("v_cvt_pk_bf16_f32 %0, %1, %2" : "=v"(u) : "v"(lo), "v"(hiv));
      int d = db * 32 + (r & 3) + 8 * (r >> 2) + 4 * hi;
      *(unsigned int*)(tr + q5 * 256 + ((d * 2) ^ swz)) = u;
    }
  asm volatile("s_waitcnt lgkmcnt(0)" ::: "memory");
#pragma unroll
  for (int p = 0; p < 8; ++p) {
    int row = (lane >> 3) + (p >> 1) * 8;
    int c = (lane & 7) + (p & 1) * 8;
    short8 v = *(const short8*)(tr + row * 256 + ((c * 16) ^ ((row & 7) << 4)));
    *(short8*)(Og + (size_t)(qrow0 + row) * 8192 + h * 128 + c * 8) = v;
  }
}

// -------------------- host --------------------
extern "C" void kernel_launch(void* const* d_in, const int* in_sizes, int n_in,
                              void* d_out, int out_size, void* d_ws, size_t ws_size,
                              hipStream_t stream) {
  const float* x = (const float*)d_in[0];
  const float* wq = (const float*)d_in[1];
  const float* wk = (const float*)d_in[2];
  const float* wv = (const float*)d_in[3];
  const float* wo = (const float*)d_in[4];
  const float* qw = (const float*)d_in[5];
  const float* kw = (const float*)d_in[6];
  const float* fc = (const float*)d_in[9];
  const float* fs = (const float*)d_in[10];

  char* ws = (char*)d_ws;
  ushort_t* Wb = (ushort_t*)(ws);
  ushort_t* qkv = (ushort_t*)(ws + 104857600);
  ushort_t* xb = (ushort_t*)(ws + 146800640);
  ushort_t* Qb = xb;
  ushort_t* Kb = (ushort_t*)(ws + 180355072);
  ushort_t* Vtb = (ushort_t*)(ws + 184549376);
  ushort_t* attnb = qkv;

  // all pre-GEMM f32->bf16 conversions in ONE launch (x, wq, wk, wv)
  cvt_all<<<dim3(30720), 256, 0, stream>>>(x, wq, wk, wv, xb, Wb);

  // qkv = x @ [wq;wk;wv]^T   (2048 x 10240 x 5120): 128x320 tiles -> 512 blocks
  // (exactly 2 uniform rounds per CU), ring-5 single-barrier schedule
  gemmR<0, 4, 5><<<dim3(16, 32), 512, 0, stream>>>(xb, Wb, qkv, 2048, 10240, 5120);

  // convert wo (reuses Wb region; must follow gemm1)
  {
    int n8 = 5120 * 8192 / 8;
    cvt_bf16<<<dim3((n8 + 255) / 256), 256, 0, stream>>>(wo, Wb, n8);
  }

  // rmsnorm + rope + split into head-major Q/K
  normrope<<<dim3(18, 2048), 256, 0, stream>>>(qkv, qw, kw, fc, fs, Qb, Kb);

  // V transpose: [s][kvh][d] -> [kvh][d][s]
  vtrans<<<dim3(32, 8), 256, 0, stream>>>(qkv, Vtb);

  // causal flash attention (kvh-per-XCD remap, heavy q-tiles first)
  attn_fwd<<<dim3(1024), 256, 0, stream>>>(Qb, Kb, Vtb, attnb);

  // out = attn @ wo^T  (2048 x 5120 x 8192), f32: 128x320 tiles -> exactly 256 blocks,
  // ring-5 single-barrier schedule
  gemmR<1, 4, 5><<<dim3(16, 16), 512, 0, stream>>>(attnb, Wb, (float*)d_out, 2048, 5120, 8192);
}

// Round 21
// 614.510 us; speedup vs baseline: 1.0576x; 1.0576x over previous
//
#include <hip/hip_runtime.h>

typedef unsigned short ushort_t;
typedef __attribute__((ext_vector_type(8))) short short8;
typedef __attribute__((ext_vector_type(4))) float f32x4;
typedef __attribute__((ext_vector_type(16))) float f32x16;

#define AS1U(p) ((const __attribute__((address_space(1))) unsigned int*)(p))
#define AS3U(p) ((__attribute__((address_space(3))) unsigned int*)(p))

__device__ __forceinline__ float bf2f(ushort_t u) {
  union { unsigned int i; float f; } v; v.i = ((unsigned int)u) << 16; return v.f;
}
__device__ __forceinline__ ushort_t f2bf(float f) {
  union { float f; unsigned int i; } v; v.f = f;
  unsigned int r = v.i + 0x7fffu + ((v.i >> 16) & 1u);
  return (ushort_t)(r >> 16);
}

template <int N>
__device__ __forceinline__ void waitvm() {
  if constexpr (N == 0) asm volatile("s_waitcnt vmcnt(0)" ::: "memory");
  else if constexpr (N == 2) asm volatile("s_waitcnt vmcnt(2)" ::: "memory");
  else if constexpr (N == 4) asm volatile("s_waitcnt vmcnt(4)" ::: "memory");
  else if constexpr (N == 5) asm volatile("s_waitcnt vmcnt(5)" ::: "memory");
  else if constexpr (N == 8) asm volatile("s_waitcnt vmcnt(8)" ::: "memory");
  else if constexpr (N == 10) asm volatile("s_waitcnt vmcnt(10)" ::: "memory");
}

// pack 8 f32 (S[base..base+7]) into short8 of bf16 via cvt_pk
#define PACK8(dst, S, base)                                                             \
  {                                                                                     \
    union { unsigned int u[4]; short8 s; } pk;                                          \
    asm("v_cvt_pk_bf16_f32 %0, %1, %2" : "=v"(pk.u[0]) : "v"(S[base + 0]), "v"(S[base + 1])); \
    asm("v_cvt_pk_bf16_f32 %0, %1, %2" : "=v"(pk.u[1]) : "v"(S[base + 2]), "v"(S[base + 3])); \
    asm("v_cvt_pk_bf16_f32 %0, %1, %2" : "=v"(pk.u[2]) : "v"(S[base + 4]), "v"(S[base + 5])); \
    asm("v_cvt_pk_bf16_f32 %0, %1, %2" : "=v"(pk.u[3]) : "v"(S[base + 6]), "v"(S[base + 7])); \
    dst = pk.s;                                                                         \
  }

// -------------------- f32 -> bf16, single launch over 4 segments --------------------
__global__ void cvt_all(const float* __restrict__ x, const float* __restrict__ wq,
                        const float* __restrict__ wk, const float* __restrict__ wv,
                        ushort_t* __restrict__ xb, ushort_t* __restrict__ Wb) {
  int i = blockIdx.x * 256 + threadIdx.x;
  const float* src;
  ushort_t* dst;
  int idx;
  if (i < 1310720) { src = x; dst = xb; idx = i; }
  else if (i < 6553600) { src = wq; dst = Wb; idx = i - 1310720; }
  else if (i < 7208960) { src = wk; dst = Wb + 41943040; idx = i - 6553600; }
  else { src = wv; dst = Wb + 47185920; idx = i - 7208960; }
  const float4* s4 = (const float4*)(src + (size_t)idx * 8);
  float4 a = s4[0], b = s4[1];
  short8 u;
  u[0] = (short)f2bf(a.x); u[1] = (short)f2bf(a.y); u[2] = (short)f2bf(a.z); u[3] = (short)f2bf(a.w);
  u[4] = (short)f2bf(b.x); u[5] = (short)f2bf(b.y); u[6] = (short)f2bf(b.z); u[7] = (short)f2bf(b.w);
  *(short8*)(dst + (size_t)idx * 8) = u;
}

// -------------------- f32 -> bf16 (8 elems/thread) --------------------
__global__ void cvt_bf16(const float* __restrict__ src, ushort_t* __restrict__ dst, int n8) {
  int i = blockIdx.x * 256 + threadIdx.x;
  if (i >= n8) return;
  const float4* s4 = (const float4*)src;
  float4 a = s4[2 * i], b = s4[2 * i + 1];
  short8 u;
  u[0] = (short)f2bf(a.x); u[1] = (short)f2bf(a.y); u[2] = (short)f2bf(a.z); u[3] = (short)f2bf(a.w);
  u[4] = (short)f2bf(b.x); u[5] = (short)f2bf(b.y); u[6] = (short)f2bf(b.z); u[7] = (short)f2bf(b.w);
  *(short8*)(dst + (size_t)i * 8) = u;
}

// -------------------- bf16 GEMM (pairs, ring-4, 2 barriers/pair): r16 proven ----------
template <int OUTF32, int MF, int NF>
__global__ __launch_bounds__(512, 2) void gemmQ(const ushort_t* __restrict__ A,
                                                const ushort_t* __restrict__ B,
                                                void* __restrict__ Cv,
                                                int M, int N, int K) {
  constexpr int BM = MF * 32, BN = NF * 64;
  constexpr int LA = BM / 64, LB = BN / 64;
  constexpr int LMAX = (LA > LB) ? LA : LB;
  constexpr int ABUF = BM * 32;
  __shared__ __align__(16) ushort_t SH[4][(BM + BN) * 32];
  const int t = threadIdx.x;
  const int lane = t & 63, w = t >> 6;
  const int wm = w >> 2, wn = w & 3;
  const int r = lane & 15, g = lane >> 4;
  const int nwg = gridDim.x * gridDim.y;
  const int l = blockIdx.y * gridDim.x + blockIdx.x;
  const int wg = (l & 7) * (nwg >> 3) + (l >> 3);
  const int m0 = (wg & (gridDim.x - 1)) * BM, n0 = (wg / gridDim.x) * BN;
  const int NT = K >> 5;
  const int t256 = t & 255;

  const ushort_t* sp[LMAX];
  int sdst[LMAX];
  if (w < 4) {
#pragma unroll
    for (int i = 0; i < LA; ++i) {
      int s = t256 + i * 256;
      int row = s >> 2, c = s & 3;
      int csrc = c ^ ((row >> 1) & 3);
      sp[i] = A + (size_t)(m0 + row) * K + csrc * 8;
      sdst[i] = s * 8;
    }
  } else {
#pragma unroll
    for (int i = 0; i < LB; ++i) {
      int s = t256 + i * 256;
      int row = s >> 2, c = s & 3;
      int csrc = c ^ ((row >> 1) & 3);
      sp[i] = B + (size_t)(n0 + row) * K + csrc * 8;
      sdst[i] = ABUF + s * 8;
    }
  }
  auto STAGE = [&](int b) {
    if (w < 4) {
#pragma unroll
      for (int i = 0; i < LA; ++i) {
        __builtin_amdgcn_global_load_lds(AS1U(sp[i]), AS3U(&SH[b][0] + sdst[i]), 16, 0, 0);
        sp[i] += 32;
      }
    } else {
#pragma unroll
      for (int i = 0; i < LB; ++i) {
        __builtin_amdgcn_global_load_lds(AS1U(sp[i]), AS3U(&SH[b][0] + sdst[i]), 16, 0, 0);
        sp[i] += 32;
      }
    }
  };

  STAGE(0); STAGE(1); STAGE(2);
  if (w < 4) waitvm<2 * LA>(); else waitvm<2 * LB>();
  __builtin_amdgcn_s_barrier();

  f32x4 acc[MF][NF] = {};
  int bsel = 0;
  const int NI = NT >> 1;
  for (int ii = 0; ii < NI; ++ii) {
    const int s3 = 2 * ii + 3, s4 = 2 * ii + 4;
    const ushort_t* As0 = &SH[bsel][0];
    const ushort_t* Bs0 = &SH[bsel][ABUF];
    const int b1 = (bsel + 1) & 3;
    const ushort_t* As1 = &SH[b1][0];
    const ushort_t* Bs1 = &SH[b1][ABUF];
    short8 bf[NF], af0[MF / 2], af1[MF / 2];

#pragma unroll
    for (int m = 0; m < MF / 2; ++m) {
      int row = wm * (MF * 16) + m * 16 + r;
      af0[m] = *(const short8*)(As0 + row * 32 + (g ^ ((row >> 1) & 3)) * 8);
    }
#pragma unroll
    for (int n = 0; n < NF; ++n) {
      int row = wn * (NF * 16) + n * 16 + r;
      bf[n] = *(const short8*)(Bs0 + row * 32 + (g ^ ((row >> 1) & 3)) * 8);
    }
    if (s3 < NT) STAGE((bsel + 3) & 3);
    __builtin_amdgcn_s_setprio(1);
#pragma unroll
    for (int m = 0; m < MF / 2; ++m)
#pragma unroll
      for (int n = 0; n < NF; ++n)
        acc[m][n] = __builtin_amdgcn_mfma_f32_16x16x32_bf16(af0[m], bf[n], acc[m][n], 0, 0, 0);
    __builtin_amdgcn_s_setprio(0);

#pragma unroll
    for (int m = 0; m < MF / 2; ++m) {
      int row = wm * (MF * 16) + (MF / 2 + m) * 16 + r;
      af1[m] = *(const short8*)(As0 + row * 32 + (g ^ ((row >> 1) & 3)) * 8);
    }
    __builtin_amdgcn_s_setprio(1);
#pragma unroll
    for (int m = 0; m < MF / 2; ++m)
#pragma unroll
      for (int n = 0; n < NF; ++n)
        acc[MF / 2 + m][n] = __builtin_amdgcn_mfma_f32_16x16x32_bf16(af1[m], bf[n], acc[MF / 2 + m][n], 0, 0, 0);
    __builtin_amdgcn_s_setprio(0);
    if (s3 < NT) {
      if (w < 4) waitvm<2 * LA>(); else waitvm<2 * LB>();
    } else if (2 * ii + 2 < NT) {
      if (w < 4) waitvm<LA>(); else waitvm<LB>();
    } else {
      waitvm<0>();
    }
    __builtin_amdgcn_s_barrier();

#pragma unroll
    for (int m = 0; m < MF / 2; ++m) {
      int row = wm * (MF * 16) + m * 16 + r;
      af0[m] = *(const short8*)(As1 + row * 32 + (g ^ ((row >> 1) & 3)) * 8);
    }
#pragma unroll
    for (int n = 0; n < NF; ++n) {
      int row = wn * (NF * 16) + n * 16 + r;
      bf[n] = *(const short8*)(Bs1 + row * 32 + (g ^ ((row >> 1) & 3)) * 8);
    }
    if (s4 < NT) STAGE(bsel);
    __builtin_amdgcn_s_setprio(1);
#pragma unroll
    for (int m = 0; m < MF / 2; ++m)
#pragma unroll
      for (int n = 0; n < NF; ++n)
        acc[m][n] = __builtin_amdgcn_mfma_f32_16x16x32_bf16(af0[m], bf[n], acc[m][n], 0, 0, 0);
    __builtin_amdgcn_s_setprio(0);

#pragma unroll
    for (int m = 0; m < MF / 2; ++m) {
      int row = wm * (MF * 16) + (MF / 2 + m) * 16 + r;
      af1[m] = *(const short8*)(As1 + row * 32 + (g ^ ((row >> 1) & 3)) * 8);
    }
    __builtin_amdgcn_s_setprio(1);
#pragma unroll
    for (int m = 0; m < MF / 2; ++m)
#pragma unroll
      for (int n = 0; n < NF; ++n)
        acc[MF / 2 + m][n] = __builtin_amdgcn_mfma_f32_16x16x32_bf16(af1[m], bf[n], acc[MF / 2 + m][n], 0, 0, 0);
    __builtin_amdgcn_s_setprio(0);
    if (s4 < NT) {
      if (w < 4) waitvm<2 * LA>(); else waitvm<2 * LB>();
    } else if (s3 < NT) {
      if (w < 4) waitvm<LA>(); else waitvm<LB>();
    } else {
      waitvm<0>();
    }
    __builtin_amdgcn_s_barrier();
    bsel = (bsel + 2) & 3;
  }

#pragma unroll
  for (int m = 0; m < MF; ++m)
#pragma unroll
    for (int n = 0; n < NF; ++n)
#pragma unroll
      for (int j = 0; j < 4; ++j) {
        int row = m0 + wm * (MF * 16) + m * 16 + g * 4 + j;
        int col = n0 + wn * (NF * 16) + n * 16 + r;
        if (OUTF32)
          ((float*)Cv)[(size_t)row * N + col] = acc[m][n][j];
        else
          ((ushort_t*)Cv)[(size_t)row * N + col] = f2bf(acc[m][n][j]);
      }
}

// -------------------- bf16 GEMM (pairs, ring-5, ONE barrier/pair) ---------------------
// Ring-5 makes both stage targets (b+3, b+4 mod 5) disjoint from this pair's read
// buffers (b, b+1), so the mid barrier is removable. One s_barrier per 64-K.
// BM=128 tiles only (143 KB LDS). Proven on gemm2 (r19).
template <int OUTF32, int MF, int NF>
__global__ __launch_bounds__(512, 2) void gemmR(const ushort_t* __restrict__ A,
                                                const ushort_t* __restrict__ B,
                                                void* __restrict__ Cv,
                                                int M, int N, int K) {
  constexpr int BM = MF * 32, BN = NF * 64;
  constexpr int LA = BM / 64, LB = BN / 64;
  constexpr int LMAX = (LA > LB) ? LA : LB;
  constexpr int ABUF = BM * 32;
  __shared__ __align__(16) ushort_t SH[5][(BM + BN) * 32];
  const int t = threadIdx.x;
  const int lane = t & 63, w = t >> 6;
  const int wm = w >> 2, wn = w & 3;
  const int r = lane & 15, g = lane >> 4;
  const int nwg = gridDim.x * gridDim.y;
  const int l = blockIdx.y * gridDim.x + blockIdx.x;
  const int wg = (l & 7) * (nwg >> 3) + (l >> 3);
  const int m0 = (wg & (gridDim.x - 1)) * BM, n0 = (wg / gridDim.x) * BN;
  const int NT = K >> 5;
  const int t256 = t & 255;

  const ushort_t* sp[LMAX];
  int sdst[LMAX];
  if (w < 4) {
#pragma unroll
    for (int i = 0; i < LA; ++i) {
      int s = t256 + i * 256;
      int row = s >> 2, c = s & 3;
      int csrc = c ^ ((row >> 1) & 3);
      sp[i] = A + (size_t)(m0 + row) * K + csrc * 8;
      sdst[i] = s * 8;
    }
  } else {
#pragma unroll
    for (int i = 0; i < LB; ++i) {
      int s = t256 + i * 256;
      int row = s >> 2, c = s & 3;
      int csrc = c ^ ((row >> 1) & 3);
      sp[i] = B + (size_t)(n0 + row) * K + csrc * 8;
      sdst[i] = ABUF + s * 8;
    }
  }
  auto STAGE = [&](int b) {
    if (w < 4) {
#pragma unroll
      for (int i = 0; i < LA; ++i) {
        __builtin_amdgcn_global_load_lds(AS1U(sp[i]), AS3U(&SH[b][0] + sdst[i]), 16, 0, 0);
        sp[i] += 32;
      }
    } else {
#pragma unroll
      for (int i = 0; i < LB; ++i) {
        __builtin_amdgcn_global_load_lds(AS1U(sp[i]), AS3U(&SH[b][0] + sdst[i]), 16, 0, 0);
        sp[i] += 32;
      }
    }
  };

  // prologue: s0,s1,s2 staged; vmcnt(L) retires s0,s1 (s2 stays in flight)
  STAGE(0); STAGE(1); STAGE(2);
  if (w < 4) waitvm<LA>(); else waitvm<LB>();
  __builtin_amdgcn_s_barrier();

  f32x4 acc[MF][NF] = {};
  int bsel = 0;
  const int NI = NT >> 1;
  for (int ii = 0; ii < NI; ++ii) {
    const int s3 = 2 * ii + 3, s4 = 2 * ii + 4;
    int b1 = bsel + 1; if (b1 >= 5) b1 -= 5;
    int b3 = bsel + 3; if (b3 >= 5) b3 -= 5;
    int b4 = bsel + 4; if (b4 >= 5) b4 -= 5;
    const ushort_t* As0 = &SH[bsel][0];
    const ushort_t* Bs0 = &SH[bsel][ABUF];
    const ushort_t* As1 = &SH[b1][0];
    const ushort_t* Bs1 = &SH[b1][ABUF];
    short8 bf[NF], af0[MF / 2], af1[MF / 2];

    // ---- ph0: sub-tile 2j (A half0 + B); stage s_{2j+3} into b3 ----
#pragma unroll
    for (int m = 0; m < MF / 2; ++m) {
      int row = wm * (MF * 16) + m * 16 + r;
      af0[m] = *(const short8*)(As0 + row * 32 + (g ^ ((row >> 1) & 3)) * 8);
    }
#pragma unroll
    for (int n = 0; n < NF; ++n) {
      int row = wn * (NF * 16) + n * 16 + r;
      bf[n] = *(const short8*)(Bs0 + row * 32 + (g ^ ((row >> 1) & 3)) * 8);
    }
    if (s3 < NT) STAGE(b3);
    __builtin_amdgcn_s_setprio(1);
#pragma unroll
    for (int m = 0; m < MF / 2; ++m)
#pragma unroll
      for (int n = 0; n < NF; ++n)
        acc[m][n] = __builtin_amdgcn_mfma_f32_16x16x32_bf16(af0[m], bf[n], acc[m][n], 0, 0, 0);
    __builtin_amdgcn_s_setprio(0);

    // ---- ph1: sub-tile 2j A half1 ----
#pragma unroll
    for (int m = 0; m < MF / 2; ++m) {
      int row = wm * (MF * 16) + (MF / 2 + m) * 16 + r;
      af1[m] = *(const short8*)(As0 + row * 32 + (g ^ ((row >> 1) & 3)) * 8);
    }
    __builtin_amdgcn_s_setprio(1);
#pragma unroll
    for (int m = 0; m < MF / 2; ++m)
#pragma unroll
      for (int n = 0; n < NF; ++n)
        acc[MF / 2 + m][n] = __builtin_amdgcn_mfma_f32_16x16x32_bf16(af1[m], bf[n], acc[MF / 2 + m][n], 0, 0, 0);
    __builtin_amdgcn_s_setprio(0);

    // ---- ph2: sub-tile 2j+1 (A half0 + B); stage s_{2j+4} into b4 ----
#pragma unroll
    for (int m = 0; m < MF / 2; ++m) {
      int row = wm * (MF * 16) + m * 16 + r;
      af0[m] = *(const short8*)(As1 + row * 32 + (g ^ ((row >> 1) & 3)) * 8);
    }
#pragma unroll
    for (int n = 0; n < NF; ++n) {
      int row = wn * (NF * 16) + n * 16 + r;
      bf[n] = *(const short8*)(Bs1 + row * 32 + (g ^ ((row >> 1) & 3)) * 8);
    }
    if (s4 < NT) STAGE(b4);
    __builtin_amdgcn_s_setprio(1);
#pragma unroll
    for (int m = 0; m < MF / 2; ++m)
#pragma unroll
      for (int n = 0; n < NF; ++n)
        acc[m][n] = __builtin_amdgcn_mfma_f32_16x16x32_bf16(af0[m], bf[n], acc[m][n], 0, 0, 0);
    __builtin_amdgcn_s_setprio(0);

    // ---- ph3: sub-tile 2j+1 A half1 ----
#pragma unroll
    for (int m = 0; m < MF / 2; ++m) {
      int row = wm * (MF * 16) + (MF / 2 + m) * 16 + r;
      af1[m] = *(const short8*)(As1 + row * 32 + (g ^ ((row >> 1) & 3)) * 8);
    }
    __builtin_amdgcn_s_setprio(1);
#pragma unroll
    for (int m = 0; m < MF / 2; ++m)
#pragma unroll
      for (int n = 0; n < NF; ++n)
        acc[MF / 2 + m][n] = __builtin_amdgcn_mfma_f32_16x16x32_bf16(af1[m], bf[n], acc[MF / 2 + m][n], 0, 0, 0);
    __builtin_amdgcn_s_setprio(0);

    // ---- boundary: retire s_{2j+2} AND s_{2j+3}; s_{2j+4} stays in flight ----
    if (s4 < NT) {
      if (w < 4) waitvm<LA>(); else waitvm<LB>();
    } else {
      waitvm<0>();
    }
    __builtin_amdgcn_s_barrier();
    bsel += 2; if (bsel >= 5) bsel -= 5;
  }

#pragma unroll
  for (int m = 0; m < MF; ++m)
#pragma unroll
    for (int n = 0; n < NF; ++n)
#pragma unroll
      for (int j = 0; j < 4; ++j) {
        int row = m0 + wm * (MF * 16) + m * 16 + g * 4 + j;
        int col = n0 + wn * (NF * 16) + n * 16 + r;
        if (OUTF32)
          ((float*)Cv)[(size_t)row * N + col] = acc[m][n][j];
        else
          ((ushort_t*)Cv)[(size_t)row * N + col] = f2bf(acc[m][n][j]);
      }
}

// -------------------- fused RMSNorm + RoPE + head split --------------------
__global__ __launch_bounds__(256) void normrope(const ushort_t* __restrict__ qkv,
                                                const float* __restrict__ qw, const float* __restrict__ kw,
                                                const float* __restrict__ fc, const float* __restrict__ fs,
                                                ushort_t* __restrict__ Qb, ushort_t* __restrict__ Kb) {
  const int slot = blockIdx.x * 4 + (threadIdx.x >> 6);
  const int s = blockIdx.y, t = threadIdx.x & 63;
  const ushort_t* src;
  ushort_t* dst;
  const float* wn;
  float scale = 1.0f;
  if (slot < 64) {
    src = qkv + (size_t)s * 10240 + slot * 128;
    dst = Qb + ((size_t)slot * 2048 + s) * 128;
    wn = qw;
    scale = 0.08838834764831845f;  // 1/sqrt(128) folded into Q
  } else {
    int kh = slot - 64;
    src = qkv + (size_t)s * 10240 + 8192 + kh * 128;
    dst = Kb + ((size_t)kh * 2048 + s) * 128;
    wn = kw;
  }
  float e0 = bf2f(src[2 * t]), e1 = bf2f(src[2 * t + 1]);
  float ss = e0 * e0 + e1 * e1;
#pragma unroll
  for (int m = 1; m < 64; m <<= 1) ss += __shfl_xor(ss, m);
  float rn = rsqrtf(ss * (1.0f / 128.0f) + 1e-6f);
  float v0 = e0 * rn * wn[2 * t], v1 = e1 * rn * wn[2 * t + 1];
  float c = fc[s * 64 + t], sn = fs[s * 64 + t];
  float oe = v0 * c - v1 * sn;
  float oo = v0 * sn + v1 * c;
  dst[2 * t] = f2bf(oe * scale);
  dst[2 * t + 1] = f2bf(oo * scale);
}

// -------------------- V transpose: qkv V-section [s][kvh*128+d] -> Vt[kvh][d][s] --------------------
__global__ __launch_bounds__(256) void vtrans(const ushort_t* __restrict__ qkv,
                                              ushort_t* __restrict__ Vt) {
  __shared__ __align__(16) ushort_t T[64 * 128];
  const int t = threadIdx.x, st = blockIdx.x, kvh = blockIdx.y;
#pragma unroll
  for (int i = 0; i < 4; ++i) {
    int slot = t + i * 256;
    int srow = slot >> 4, c8 = slot & 15;
    short8 v = *(const short8*)(qkv + (size_t)(st * 64 + srow) * 10240 + 9216 + kvh * 128 + c8 * 8);
    int sw = (((srow & 7) ^ ((srow >> 3) & 7)) << 4);
    *(short8*)((char*)T + srow * 256 + ((c8 * 16) ^ sw)) = v;
  }
  __syncthreads();
#pragma unroll
  for (int i = 0; i < 4; ++i) {
    int slot = t + i * 256;
    int d = slot >> 3, s8 = slot & 7;
    short8 u;
#pragma unroll
    for (int j = 0; j < 8; ++j) {
      int row = s8 * 8 + j;
      int sw = (((row & 7) ^ ((row >> 3) & 7)) << 4);
      u[j] = *(const ushort_t*)((char*)T + row * 256 + ((d * 2) ^ sw));
    }
    *(short8*)(Vt + ((size_t)kvh * 128 + d) * 2048 + st * 64 + s8 * 8) = u;
  }
}

// -------------------- causal flash attention (GQA 8:1), swapped-QK^T 32x32 --------------------
// grid 1024 linear; block remap lb -> (kvh=lb&7, hsub=(lb>>3)&7, qt=15-(lb>>6)):
// all 8 q-heads of one KV head land on ONE XCD (KV 1MB << 4MB L2), heavy qt first.
__global__ __launch_bounds__(256) void attn_fwd(const ushort_t* __restrict__ Qg,
                                                const ushort_t* __restrict__ Kg,
                                                const ushort_t* __restrict__ VtG,
                                                ushort_t* __restrict__ Og) {
  __shared__ __align__(16) ushort_t Ks[2][64 * 128];   // [kv][d], chunk-XOR swizzled
  __shared__ __align__(16) ushort_t Vs[2][128 * 64];   // [d][kv], chunk-XOR swizzled
  const int t = threadIdx.x, lane = t & 63, w = t >> 6;
  const int q5 = lane & 31, hi = lane >> 5;
  const int lb = blockIdx.x;
  const int kvh = lb & 7;
  const int h = kvh * 8 + ((lb >> 3) & 7);
  const int qt = 15 - (lb >> 6);
  const int qrow0 = qt * 128 + w * 32;
  const int qglob = qrow0 + q5;

  // permuted K row for the S^T A-operand: m = q5 -> kr = g(m)
  const int pa = q5 & 3, pp = (q5 >> 2) & 1, pb = q5 >> 3;
  const int kr = (pb >> 1) * 16 + pp * 8 + (pb & 1) * 4 + pa;
  const int kswz = (kr & 7) << 4;
  const int swz = (q5 & 7) << 4;

  // Q fragments (B-operand): col q = q5, k-slice = hi*8; 8 k-steps of 16
  short8 qf[8];
#pragma unroll
  for (int ks = 0; ks < 8; ++ks)
    qf[ks] = *(const short8*)(Qg + ((size_t)h * 2048 + qglob) * 128 + ks * 16 + hi * 8);

  f32x16 o[4] = {};
  float mrun = -3.0e38f, lrun = 0.0f;

  const int kbmax_blk = 2 * qt + 1;
  const int kbmax_w = (qrow0 + 31) >> 6;

  auto STAGE = [&](int b, int kb) {
#pragma unroll
    for (int i = 0; i < 4; ++i) {
      int slot = t + i * 256;                    // 1024 16B slots (K)
      int kv = slot >> 4, c = slot & 15;
      int csrc = c ^ (kv & 7);
      __builtin_amdgcn_global_load_lds(AS1U(Kg + ((size_t)kvh * 2048 + kb * 64 + kv) * 128 + csrc * 8),
                                       AS3U(&Ks[b][0] + slot * 8), 16, 0, 0);
    }
#pragma unroll
    for (int i = 0; i < 4; ++i) {
      int slot = t + i * 256;                    // 1024 16B slots (V^T)
      int d = slot >> 3, c = slot & 7;
      int csrc = c ^ (d & 7);
      __builtin_amdgcn_global_load_lds(AS1U(VtG + ((size_t)kvh * 128 + d) * 2048 + kb * 64 + csrc * 8),
                                       AS3U(&Vs[b][0] + slot * 8), 16, 0, 0);
    }
  };

  STAGE(0, 0);
  int cur = 0;

  for (int kb = 0; kb <= kbmax_blk; ++kb) {
    asm volatile("s_waitcnt vmcnt(0)" ::: "memory");
    __syncthreads();
    if (kb < kbmax_blk) STAGE(cur ^ 1, kb + 1);

    if (kb <= kbmax_w) {
      const char* kbase = (const char*)&Ks[cur][0];
      const char* vbase = (const char*)&Vs[cur][0];

      // ---- S^T = K_perm · Q^T ----
      f32x16 st0 = {}, st1 = {};
#pragma unroll
      for (int ks = 0; ks < 8; ++ks) {
        int cslot = ((ks * 2 + hi) * 16) ^ kswz;
        short8 kf0 = *(const short8*)(kbase + kr * 256 + cslot);
        short8 kf1 = *(const short8*)(kbase + (32 + kr) * 256 + cslot);
        __builtin_amdgcn_s_setprio(1);
        st0 = __builtin_amdgcn_mfma_f32_32x32x16_bf16(kf0, qf[ks], st0, 0, 0, 0);
        st1 = __builtin_amdgcn_mfma_f32_32x32x16_bf16(kf1, qf[ks], st1, 0, 0, 0);
        __builtin_amdgcn_s_setprio(0);
      }

      if (kb == kbmax_w) {
#pragma unroll
        for (int r = 0; r < 16; ++r) {
          int kv0 = kb * 64 + (r >> 3) * 16 + hi * 8 + (r & 7);
          if (kv0 > qglob) st0[r] = -1.0e30f;
          if (kv0 + 32 > qglob) st1[r] = -1.0e30f;
        }
      }

      float pmax = st0[0];
#pragma unroll
      for (int r = 1; r < 16; ++r) pmax = fmaxf(pmax, st0[r]);
#pragma unroll
      for (int r = 0; r < 16; ++r) pmax = fmaxf(pmax, st1[r]);
      pmax = fmaxf(pmax, __shfl_xor(pmax, 32));
      if (!__all(pmax <= mrun + 8.0f)) {
        float mn = fmaxf(mrun, pmax);
        float sc = __expf(mrun - mn);
        mrun = mn;
        lrun *= sc;
#pragma unroll
        for (int db = 0; db < 4; ++db) o[db] *= sc;
      }
      float rs = 0.0f;
#pragma unroll
      for (int r = 0; r < 16; ++r) { st0[r] = __expf(st0[r] - mrun); rs += st0[r]; }
#pragma unroll
      for (int r = 0; r < 16; ++r) { st1[r] = __expf(st1[r] - mrun); rs += st1[r]; }
      rs += __shfl_xor(rs, 32);
      lrun += rs;

      short8 pf[4];
      PACK8(pf[0], st0, 0);
      PACK8(pf[1], st0, 8);
      PACK8(pf[2], st1, 0);
      PACK8(pf[3], st1, 8);

#pragma unroll
      for (int db = 0; db < 4; ++db) {
#pragma unroll
        for (int ks = 0; ks < 4; ++ks) {
          short8 vf = *(const short8*)(vbase + (db * 32 + q5) * 128 + ((((ks * 2 + hi) * 16)) ^ swz));
          __builtin_amdgcn_s_setprio(1);
          o[db] = __builtin_amdgcn_mfma_f32_32x32x16_bf16(vf, pf[ks], o[db], 0, 0, 0);
          __builtin_amdgcn_s_setprio(0);
        }
      }
    }
    cur ^= 1;
  }

  // ---- epilogue: normalize, transpose via LDS, coalesced store ----
  __syncthreads();
  char* tr = ((char*)Ks) + w * 8192;
  float inv = 1.0f / lrun;
#pragma unroll
  for (int db = 0; db < 4; ++db)
#pragma unroll
    for (int r = 0; r < 16; r += 2) {
      unsigned int u;
      float lo = o[db][r] * inv, hiv = o[db][r + 1] * inv;
      asm("v_cvt_pk_bf16_f32 %0, %1, %2" : "=v"(u) : "v"(lo), "v"(hiv));
      int d = db * 32 + (r & 3) + 8 * (r >> 2) + 4 * hi;
      *(unsigned int*)(tr + q5 * 256 + ((d * 2) ^ swz)) = u;
    }
  asm volatile("s_waitcnt lgkmcnt(0)" ::: "memory");
#pragma unroll
  for (int p = 0; p < 8; ++p) {
    int row = (lane >> 3) + (p >> 1) * 8;
    int c = (lane & 7) + (p & 1) * 8;
    short8 v = *(const short8*)(tr + row * 256 + ((c * 16) ^ ((row & 7) << 4)));
    *(short8*)(Og + (size_t)(qrow0 + row) * 8192 + h * 128 + c * 8) = v;
  }
}

// -------------------- host --------------------
extern "C" void kernel_launch(void* const* d_in, const int* in_sizes, int n_in,
                              void* d_out, int out_size, void* d_ws, size_t ws_size,
                              hipStream_t stream) {
  const float* x = (const float*)d_in[0];
  const float* wq = (const float*)d_in[1];
  const float* wk = (const float*)d_in[2];
  const float* wv = (const float*)d_in[3];
  const float* wo = (const float*)d_in[4];
  const float* qw = (const float*)d_in[5];
  const float* kw = (const float*)d_in[6];
  const float* fc = (const float*)d_in[9];
  const float* fs = (const float*)d_in[10];

  char* ws = (char*)d_ws;
  ushort_t* Wb = (ushort_t*)(ws);
  ushort_t* qkv = (ushort_t*)(ws + 104857600);
  ushort_t* xb = (ushort_t*)(ws + 146800640);
  ushort_t* Qb = xb;
  ushort_t* Kb = (ushort_t*)(ws + 180355072);
  ushort_t* Vtb = (ushort_t*)(ws + 184549376);
  ushort_t* attnb = qkv;

  // all pre-GEMM f32->bf16 conversions in ONE launch (x, wq, wk, wv)
  cvt_all<<<dim3(30720), 256, 0, stream>>>(x, wq, wk, wv, xb, Wb);

  // qkv = x @ [wq;wk;wv]^T   (2048 x 10240 x 5120): 256x320 tiles -> exactly 256 blocks
  gemmQ<0, 8, 5><<<dim3(8, 32), 512, 0, stream>>>(xb, Wb, qkv, 2048, 10240, 5120);

  // convert wo (reuses Wb region; must follow gemm1)
  {
    int n8 = 5120 * 8192 / 8;
    cvt_bf16<<<dim3((n8 + 255) / 256), 256, 0, stream>>>(wo, Wb, n8);
  }

  // rmsnorm + rope + split into head-major Q/K
  normrope<<<dim3(18, 2048), 256, 0, stream>>>(qkv, qw, kw, fc, fs, Qb, Kb);

  // V transpose: [s][kvh][d] -> [kvh][d][s]
  vtrans<<<dim3(32, 8), 256, 0, stream>>>(qkv, Vtb);

  // causal flash attention (kvh-per-XCD remap, heavy q-tiles first)
  attn_fwd<<<dim3(1024), 256, 0, stream>>>(Qb, Kb, Vtb, attnb);

  // out = attn @ wo^T  (2048 x 5120 x 8192), f32: 128x320 tiles -> exactly 256 blocks,
  // ring-5 single-barrier schedule
  gemmR<1, 4, 5><<<dim3(16, 16), 512, 0, stream>>>(attnb, Wb, (float*)d_out, 2048, 5120, 8192);
}

// Round 23
// 552.667 us; speedup vs baseline: 1.1760x; 1.1119x over previous
//
#include <hip/hip_runtime.h>

typedef unsigned short ushort_t;
typedef __attribute__((ext_vector_type(8))) short short8;
typedef __attribute__((ext_vector_type(4))) float f32x4;
typedef __attribute__((ext_vector_type(16))) float f32x16;

#define AS1U(p) ((const __attribute__((address_space(1))) unsigned int*)(p))
#define AS3U(p) ((__attribute__((address_space(3))) unsigned int*)(p))

__device__ __forceinline__ float bf2f(ushort_t u) {
  union { unsigned int i; float f; } v; v.i = ((unsigned int)u) << 16; return v.f;
}
__device__ __forceinline__ ushort_t f2bf(float f) {
  union { float f; unsigned int i; } v; v.f = f;
  unsigned int r = v.i + 0x7fffu + ((v.i >> 16) & 1u);
  return (ushort_t)(r >> 16);
}

template <int N>
__device__ __forceinline__ void waitvm() {
  if constexpr (N == 0) asm volatile("s_waitcnt vmcnt(0)" ::: "memory");
  else if constexpr (N == 2) asm volatile("s_waitcnt vmcnt(2)" ::: "memory");
  else if constexpr (N == 4) asm volatile("s_waitcnt vmcnt(4)" ::: "memory");
  else if constexpr (N == 5) asm volatile("s_waitcnt vmcnt(5)" ::: "memory");
  else if constexpr (N == 8) asm volatile("s_waitcnt vmcnt(8)" ::: "memory");
  else if constexpr (N == 10) asm volatile("s_waitcnt vmcnt(10)" ::: "memory");
}

// pack 8 f32 (S[base..base+7]) into short8 of bf16 via cvt_pk
#define PACK8(dst, S, base)                                                             \
  {                                                                                     \
    union { unsigned int u[4]; short8 s; } pk;                                          \
    asm("v_cvt_pk_bf16_f32 %0, %1, %2" : "=v"(pk.u[0]) : "v"(S[base + 0]), "v"(S[base + 1])); \
    asm("v_cvt_pk_bf16_f32 %0, %1, %2" : "=v"(pk.u[1]) : "v"(S[base + 2]), "v"(S[base + 3])); \
    asm("v_cvt_pk_bf16_f32 %0, %1, %2" : "=v"(pk.u[2]) : "v"(S[base + 4]), "v"(S[base + 5])); \
    asm("v_cvt_pk_bf16_f32 %0, %1, %2" : "=v"(pk.u[3]) : "v"(S[base + 6]), "v"(S[base + 7])); \
    dst = pk.s;                                                                         \
  }

// -------------------- f32 -> bf16, single launch over 4 segments --------------------
__global__ void cvt_all(const float* __restrict__ x, const float* __restrict__ wq,
                        const float* __restrict__ wk, const float* __restrict__ wv,
                        ushort_t* __restrict__ xb, ushort_t* __restrict__ Wb) {
  int i = blockIdx.x * 256 + threadIdx.x;
  const float* src;
  ushort_t* dst;
  int idx;
  if (i < 1310720) { src = x; dst = xb; idx = i; }
  else if (i < 6553600) { src = wq; dst = Wb; idx = i - 1310720; }
  else if (i < 7208960) { src = wk; dst = Wb + 41943040; idx = i - 6553600; }
  else { src = wv; dst = Wb + 47185920; idx = i - 7208960; }
  const float4* s4 = (const float4*)(src + (size_t)idx * 8);
  float4 a = s4[0], b = s4[1];
  short8 u;
  u[0] = (short)f2bf(a.x); u[1] = (short)f2bf(a.y); u[2] = (short)f2bf(a.z); u[3] = (short)f2bf(a.w);
  u[4] = (short)f2bf(b.x); u[5] = (short)f2bf(b.y); u[6] = (short)f2bf(b.z); u[7] = (short)f2bf(b.w);
  *(short8*)(dst + (size_t)idx * 8) = u;
}

// -------------------- f32 -> bf16 (8 elems/thread) --------------------
__global__ void cvt_bf16(const float* __restrict__ src, ushort_t* __restrict__ dst, int n8) {
  int i = blockIdx.x * 256 + threadIdx.x;
  if (i >= n8) return;
  const float4* s4 = (const float4*)src;
  float4 a = s4[2 * i], b = s4[2 * i + 1];
  short8 u;
  u[0] = (short)f2bf(a.x); u[1] = (short)f2bf(a.y); u[2] = (short)f2bf(a.z); u[3] = (short)f2bf(a.w);
  u[4] = (short)f2bf(b.x); u[5] = (short)f2bf(b.y); u[6] = (short)f2bf(b.z); u[7] = (short)f2bf(b.w);
  *(short8*)(dst + (size_t)i * 8) = u;
}

// -------------------- bf16 GEMM (pairs, ring-4, 2 barriers/pair): r16 proven ----------
template <int OUTF32, int MF, int NF>
__global__ __launch_bounds__(512, 2) void gemmQ(const ushort_t* __restrict__ A,
                                                const ushort_t* __restrict__ B,
                                                void* __restrict__ Cv,
                                                int M, int N, int K) {
  constexpr int BM = MF * 32, BN = NF * 64;
  constexpr int LA = BM / 64, LB = BN / 64;
  constexpr int LMAX = (LA > LB) ? LA : LB;
  constexpr int ABUF = BM * 32;
  __shared__ __align__(16) ushort_t SH[4][(BM + BN) * 32];
  const int t = threadIdx.x;
  const int lane = t & 63, w = t >> 6;
  const int wm = w >> 2, wn = w & 3;
  const int r = lane & 15, g = lane >> 4;
  const int nwg = gridDim.x * gridDim.y;
  const int l = blockIdx.y * gridDim.x + blockIdx.x;
  const int wg = (l & 7) * (nwg >> 3) + (l >> 3);
  const int m0 = (wg & (gridDim.x - 1)) * BM, n0 = (wg / gridDim.x) * BN;
  const int NT = K >> 5;
  const int t256 = t & 255;

  const ushort_t* sp[LMAX];
  int sdst[LMAX];
  if (w < 4) {
#pragma unroll
    for (int i = 0; i < LA; ++i) {
      int s = t256 + i * 256;
      int row = s >> 2, c = s & 3;
      int csrc = c ^ ((row >> 1) & 3);
      sp[i] = A + (size_t)(m0 + row) * K + csrc * 8;
      sdst[i] = s * 8;
    }
  } else {
#pragma unroll
    for (int i = 0; i < LB; ++i) {
      int s = t256 + i * 256;
      int row = s >> 2, c = s & 3;
      int csrc = c ^ ((row >> 1) & 3);
      sp[i] = B + (size_t)(n0 + row) * K + csrc * 8;
      sdst[i] = ABUF + s * 8;
    }
  }
  auto STAGE = [&](int b) {
    if (w < 4) {
#pragma unroll
      for (int i = 0; i < LA; ++i) {
        __builtin_amdgcn_global_load_lds(AS1U(sp[i]), AS3U(&SH[b][0] + sdst[i]), 16, 0, 0);
        sp[i] += 32;
      }
    } else {
#pragma unroll
      for (int i = 0; i < LB; ++i) {
        __builtin_amdgcn_global_load_lds(AS1U(sp[i]), AS3U(&SH[b][0] + sdst[i]), 16, 0, 0);
        sp[i] += 32;
      }
    }
  };

  STAGE(0); STAGE(1); STAGE(2);
  if (w < 4) waitvm<2 * LA>(); else waitvm<2 * LB>();
  __builtin_amdgcn_s_barrier();

  f32x4 acc[MF][NF] = {};
  int bsel = 0;
  const int NI = NT >> 1;
  for (int ii = 0; ii < NI; ++ii) {
    const int s3 = 2 * ii + 3, s4 = 2 * ii + 4;
    const ushort_t* As0 = &SH[bsel][0];
    const ushort_t* Bs0 = &SH[bsel][ABUF];
    const int b1 = (bsel + 1) & 3;
    const ushort_t* As1 = &SH[b1][0];
    const ushort_t* Bs1 = &SH[b1][ABUF];
    short8 bf[NF], af0[MF / 2], af1[MF / 2];

#pragma unroll
    for (int m = 0; m < MF / 2; ++m) {
      int row = wm * (MF * 16) + m * 16 + r;
      af0[m] = *(const short8*)(As0 + row * 32 + (g ^ ((row >> 1) & 3)) * 8);
    }
#pragma unroll
    for (int n = 0; n < NF; ++n) {
      int row = wn * (NF * 16) + n * 16 + r;
      bf[n] = *(const short8*)(Bs0 + row * 32 + (g ^ ((row >> 1) & 3)) * 8);
    }
    if (s3 < NT) STAGE((bsel + 3) & 3);
    __builtin_amdgcn_s_setprio(1);
#pragma unroll
    for (int m = 0; m < MF / 2; ++m)
#pragma unroll
      for (int n = 0; n < NF; ++n)
        acc[m][n] = __builtin_amdgcn_mfma_f32_16x16x32_bf16(af0[m], bf[n], acc[m][n], 0, 0, 0);
    __builtin_amdgcn_s_setprio(0);

#pragma unroll
    for (int m = 0; m < MF / 2; ++m) {
      int row = wm * (MF * 16) + (MF / 2 + m) * 16 + r;
      af1[m] = *(const short8*)(As0 + row * 32 + (g ^ ((row >> 1) & 3)) * 8);
    }
    __builtin_amdgcn_s_setprio(1);
#pragma unroll
    for (int m = 0; m < MF / 2; ++m)
#pragma unroll
      for (int n = 0; n < NF; ++n)
        acc[MF / 2 + m][n] = __builtin_amdgcn_mfma_f32_16x16x32_bf16(af1[m], bf[n], acc[MF / 2 + m][n], 0, 0, 0);
    __builtin_amdgcn_s_setprio(0);
    if (s3 < NT) {
      if (w < 4) waitvm<2 * LA>(); else waitvm<2 * LB>();
    } else if (2 * ii + 2 < NT) {
      if (w < 4) waitvm<LA>(); else waitvm<LB>();
    } else {
      waitvm<0>();
    }
    __builtin_amdgcn_s_barrier();

#pragma unroll
    for (int m = 0; m < MF / 2; ++m) {
      int row = wm * (MF * 16) + m * 16 + r;
      af0[m] = *(const short8*)(As1 + row * 32 + (g ^ ((row >> 1) & 3)) * 8);
    }
#pragma unroll
    for (int n = 0; n < NF; ++n) {
      int row = wn * (NF * 16) + n * 16 + r;
      bf[n] = *(const short8*)(Bs1 + row * 32 + (g ^ ((row >> 1) & 3)) * 8);
    }
    if (s4 < NT) STAGE(bsel);
    __builtin_amdgcn_s_setprio(1);
#pragma unroll
    for (int m = 0; m < MF / 2; ++m)
#pragma unroll
      for (int n = 0; n < NF; ++n)
        acc[m][n] = __builtin_amdgcn_mfma_f32_16x16x32_bf16(af0[m], bf[n], acc[m][n], 0, 0, 0);
    __builtin_amdgcn_s_setprio(0);

#pragma unroll
    for (int m = 0; m < MF / 2; ++m) {
      int row = wm * (MF * 16) + (MF / 2 + m) * 16 + r;
      af1[m] = *(const short8*)(As1 + row * 32 + (g ^ ((row >> 1) & 3)) * 8);
    }
    __builtin_amdgcn_s_setprio(1);
#pragma unroll
    for (int m = 0; m < MF / 2; ++m)
#pragma unroll
      for (int n = 0; n < NF; ++n)
        acc[MF / 2 + m][n] = __builtin_amdgcn_mfma_f32_16x16x32_bf16(af1[m], bf[n], acc[MF / 2 + m][n], 0, 0, 0);
    __builtin_amdgcn_s_setprio(0);
    if (s4 < NT) {
      if (w < 4) waitvm<2 * LA>(); else waitvm<2 * LB>();
    } else if (s3 < NT) {
      if (w < 4) waitvm<LA>(); else waitvm<LB>();
    } else {
      waitvm<0>();
    }
    __builtin_amdgcn_s_barrier();
    bsel = (bsel + 2) & 3;
  }

#pragma unroll
  for (int m = 0; m < MF; ++m)
#pragma unroll
    for (int n = 0; n < NF; ++n)
#pragma unroll
      for (int j = 0; j < 4; ++j) {
        int row = m0 + wm * (MF * 16) + m * 16 + g * 4 + j;
        int col = n0 + wn * (NF * 16) + n * 16 + r;
        if (OUTF32)
          ((float*)Cv)[(size_t)row * N + col] = acc[m][n][j];
        else
          ((ushort_t*)Cv)[(size_t)row * N + col] = f2bf(acc[m][n][j]);
      }
}

// -------------------- bf16 GEMM (pairs, ring-5, ONE barrier/pair): r19 proven --------
template <int OUTF32, int MF, int NF>
__global__ __launch_bounds__(512, 2) void gemmR(const ushort_t* __restrict__ A,
                                                const ushort_t* __restrict__ B,
                                                void* __restrict__ Cv,
                                                int M, int N, int K) {
  constexpr int BM = MF * 32, BN = NF * 64;
  constexpr int LA = BM / 64, LB = BN / 64;
  constexpr int LMAX = (LA > LB) ? LA : LB;
  constexpr int ABUF = BM * 32;
  __shared__ __align__(16) ushort_t SH[5][(BM + BN) * 32];
  const int t = threadIdx.x;
  const int lane = t & 63, w = t >> 6;
  const int wm = w >> 2, wn = w & 3;
  const int r = lane & 15, g = lane >> 4;
  const int nwg = gridDim.x * gridDim.y;
  const int l = blockIdx.y * gridDim.x + blockIdx.x;
  const int wg = (l & 7) * (nwg >> 3) + (l >> 3);
  const int m0 = (wg & (gridDim.x - 1)) * BM, n0 = (wg / gridDim.x) * BN;
  const int NT = K >> 5;
  const int t256 = t & 255;

  const ushort_t* sp[LMAX];
  int sdst[LMAX];
  if (w < 4) {
#pragma unroll
    for (int i = 0; i < LA; ++i) {
      int s = t256 + i * 256;
      int row = s >> 2, c = s & 3;
      int csrc = c ^ ((row >> 1) & 3);
      sp[i] = A + (size_t)(m0 + row) * K + csrc * 8;
      sdst[i] = s * 8;
    }
  } else {
#pragma unroll
    for (int i = 0; i < LB; ++i) {
      int s = t256 + i * 256;
      int row = s >> 2, c = s & 3;
      int csrc = c ^ ((row >> 1) & 3);
      sp[i] = B + (size_t)(n0 + row) * K + csrc * 8;
      sdst[i] = ABUF + s * 8;
    }
  }
  auto STAGE = [&](int b) {
    if (w < 4) {
#pragma unroll
      for (int i = 0; i < LA; ++i) {
        __builtin_amdgcn_global_load_lds(AS1U(sp[i]), AS3U(&SH[b][0] + sdst[i]), 16, 0, 0);
        sp[i] += 32;
      }
    } else {
#pragma unroll
      for (int i = 0; i < LB; ++i) {
        __builtin_amdgcn_global_load_lds(AS1U(sp[i]), AS3U(&SH[b][0] + sdst[i]), 16, 0, 0);
        sp[i] += 32;
      }
    }
  };

  STAGE(0); STAGE(1); STAGE(2);
  if (w < 4) waitvm<LA>(); else waitvm<LB>();
  __builtin_amdgcn_s_barrier();

  f32x4 acc[MF][NF] = {};
  int bsel = 0;
  const int NI = NT >> 1;
  for (int ii = 0; ii < NI; ++ii) {
    const int s3 = 2 * ii + 3, s4 = 2 * ii + 4;
    int b1 = bsel + 1; if (b1 >= 5) b1 -= 5;
    int b3 = bsel + 3; if (b3 >= 5) b3 -= 5;
    int b4 = bsel + 4; if (b4 >= 5) b4 -= 5;
    const ushort_t* As0 = &SH[bsel][0];
    const ushort_t* Bs0 = &SH[bsel][ABUF];
    const ushort_t* As1 = &SH[b1][0];
    const ushort_t* Bs1 = &SH[b1][ABUF];
    short8 bf[NF], af0[MF / 2], af1[MF / 2];

#pragma unroll
    for (int m = 0; m < MF / 2; ++m) {
      int row = wm * (MF * 16) + m * 16 + r;
      af0[m] = *(const short8*)(As0 + row * 32 + (g ^ ((row >> 1) & 3)) * 8);
    }
#pragma unroll
    for (int n = 0; n < NF; ++n) {
      int row = wn * (NF * 16) + n * 16 + r;
      bf[n] = *(const short8*)(Bs0 + row * 32 + (g ^ ((row >> 1) & 3)) * 8);
    }
    if (s3 < NT) STAGE(b3);
    __builtin_amdgcn_s_setprio(1);
#pragma unroll
    for (int m = 0; m < MF / 2; ++m)
#pragma unroll
      for (int n = 0; n < NF; ++n)
        acc[m][n] = __builtin_amdgcn_mfma_f32_16x16x32_bf16(af0[m], bf[n], acc[m][n], 0, 0, 0);
    __builtin_amdgcn_s_setprio(0);

#pragma unroll
    for (int m = 0; m < MF / 2; ++m) {
      int row = wm * (MF * 16) + (MF / 2 + m) * 16 + r;
      af1[m] = *(const short8*)(As0 + row * 32 + (g ^ ((row >> 1) & 3)) * 8);
    }
    __builtin_amdgcn_s_setprio(1);
#pragma unroll
    for (int m = 0; m < MF / 2; ++m)
#pragma unroll
      for (int n = 0; n < NF; ++n)
        acc[MF / 2 + m][n] = __builtin_amdgcn_mfma_f32_16x16x32_bf16(af1[m], bf[n], acc[MF / 2 + m][n], 0, 0, 0);
    __builtin_amdgcn_s_setprio(0);

#pragma unroll
    for (int m = 0; m < MF / 2; ++m) {
      int row = wm * (MF * 16) + m * 16 + r;
      af0[m] = *(const short8*)(As1 + row * 32 + (g ^ ((row >> 1) & 3)) * 8);
    }
#pragma unroll
    for (int n = 0; n < NF; ++n) {
      int row = wn * (NF * 16) + n * 16 + r;
      bf[n] = *(const short8*)(Bs1 + row * 32 + (g ^ ((row >> 1) & 3)) * 8);
    }
    if (s4 < NT) STAGE(b4);
    __builtin_amdgcn_s_setprio(1);
#pragma unroll
    for (int m = 0; m < MF / 2; ++m)
#pragma unroll
      for (int n = 0; n < NF; ++n)
        acc[m][n] = __builtin_amdgcn_mfma_f32_16x16x32_bf16(af0[m], bf[n], acc[m][n], 0, 0, 0);
    __builtin_amdgcn_s_setprio(0);

#pragma unroll
    for (int m = 0; m < MF / 2; ++m) {
      int row = wm * (MF * 16) + (MF / 2 + m) * 16 + r;
      af1[m] = *(const short8*)(As1 + row * 32 + (g ^ ((row >> 1) & 3)) * 8);
    }
    __builtin_amdgcn_s_setprio(1);
#pragma unroll
    for (int m = 0; m < MF / 2; ++m)
#pragma unroll
      for (int n = 0; n < NF; ++n)
        acc[MF / 2 + m][n] = __builtin_amdgcn_mfma_f32_16x16x32_bf16(af1[m], bf[n], acc[MF / 2 + m][n], 0, 0, 0);
    __builtin_amdgcn_s_setprio(0);

    if (s4 < NT) {
      if (w < 4) waitvm<LA>(); else waitvm<LB>();
    } else {
      waitvm<0>();
    }
    __builtin_amdgcn_s_barrier();
    bsel += 2; if (bsel >= 5) bsel -= 5;
  }

#pragma unroll
  for (int m = 0; m < MF; ++m)
#pragma unroll
    for (int n = 0; n < NF; ++n)
#pragma unroll
      for (int j = 0; j < 4; ++j) {
        int row = m0 + wm * (MF * 16) + m * 16 + g * 4 + j;
        int col = n0 + wn * (NF * 16) + n * 16 + r;
        if (OUTF32)
          ((float*)Cv)[(size_t)row * N + col] = acc[m][n][j];
        else
          ((ushort_t*)Cv)[(size_t)row * N + col] = f2bf(acc[m][n][j]);
      }
}

// -------------------- fused RMSNorm + RoPE + head split --------------------
__global__ __launch_bounds__(256) void normrope(const ushort_t* __restrict__ qkv,
                                                const float* __restrict__ qw, const float* __restrict__ kw,
                                                const float* __restrict__ fc, const float* __restrict__ fs,
                                                ushort_t* __restrict__ Qb, ushort_t* __restrict__ Kb) {
  const int slot = blockIdx.x * 4 + (threadIdx.x >> 6);
  const int s = blockIdx.y, t = threadIdx.x & 63;
  const ushort_t* src;
  ushort_t* dst;
  const float* wn;
  float scale = 1.0f;
  if (slot < 64) {
    src = qkv + (size_t)s * 10240 + slot * 128;
    dst = Qb + ((size_t)slot * 2048 + s) * 128;
    wn = qw;
    scale = 0.08838834764831845f;  // 1/sqrt(128) folded into Q
  } else {
    int kh = slot - 64;
    src = qkv + (size_t)s * 10240 + 8192 + kh * 128;
    dst = Kb + ((size_t)kh * 2048 + s) * 128;
    wn = kw;
  }
  float e0 = bf2f(src[2 * t]), e1 = bf2f(src[2 * t + 1]);
  float ss = e0 * e0 + e1 * e1;
#pragma unroll
  for (int m = 1; m < 64; m <<= 1) ss += __shfl_xor(ss, m);
  float rn = rsqrtf(ss * (1.0f / 128.0f) + 1e-6f);
  float v0 = e0 * rn * wn[2 * t], v1 = e1 * rn * wn[2 * t + 1];
  float c = fc[s * 64 + t], sn = fs[s * 64 + t];
  float oe = v0 * c - v1 * sn;
  float oo = v0 * sn + v1 * c;
  dst[2 * t] = f2bf(oe * scale);
  dst[2 * t + 1] = f2bf(oo * scale);
}

// -------------------- V transpose: qkv V-section [s][kvh*128+d] -> Vt[kvh][d][s] --------------------
__global__ __launch_bounds__(256) void vtrans(const ushort_t* __restrict__ qkv,
                                              ushort_t* __restrict__ Vt) {
  __shared__ __align__(16) ushort_t T[64 * 128];
  const int t = threadIdx.x, st = blockIdx.x, kvh = blockIdx.y;
#pragma unroll
  for (int i = 0; i < 4; ++i) {
    int slot = t + i * 256;
    int srow = slot >> 4, c8 = slot & 15;
    short8 v = *(const short8*)(qkv + (size_t)(st * 64 + srow) * 10240 + 9216 + kvh * 128 + c8 * 8);
    int sw = (((srow & 7) ^ ((srow >> 3) & 7)) << 4);
    *(short8*)((char*)T + srow * 256 + ((c8 * 16) ^ sw)) = v;
  }
  __syncthreads();
#pragma unroll
  for (int i = 0; i < 4; ++i) {
    int slot = t + i * 256;
    int d = slot >> 3, s8 = slot & 7;
    short8 u;
#pragma unroll
    for (int j = 0; j < 8; ++j) {
      int row = s8 * 8 + j;
      int sw = (((row & 7) ^ ((row >> 3) & 7)) << 4);
      u[j] = *(const ushort_t*)((char*)T + row * 256 + ((d * 2) ^ sw));
    }
    *(short8*)(Vt + ((size_t)kvh * 128 + d) * 2048 + st * 64 + s8 * 8) = u;
  }
}

// -------------------- causal flash attention (GQA 8:1), swapped-QK^T 32x32 --------------------
// 512 blocks x 512 threads (8 waves). Block owns 256 q rows (qt in 0..7); each wave
// 32 rows -- per-wave math identical to the proven 4-wave version; staging tiles
// HALVED (KV reused across 256 q rows). Remap lb -> (kvh=lb&7, hsub, qt=7-(lb>>6)):
// kvh per XCD, heavy q-tiles first. LDS 64 KB arena: K dbuf [0,16K) | V dbuf
// [16K,32K) in ushort units; reused as per-wave 8KB transpose scratch in epilogue.
__global__ __launch_bounds__(512) void attn_fwd(const ushort_t* __restrict__ Qg,
                                                const ushort_t* __restrict__ Kg,
                                                const ushort_t* __restrict__ VtG,
                                                ushort_t* __restrict__ Og) {
  __shared__ __align__(16) ushort_t SM[32768];   // 64 KB
  const int t = threadIdx.x, lane = t & 63, w = t >> 6;   // w in 0..7
  const int q5 = lane & 31, hi = lane >> 5;
  const int lb = blockIdx.x;
  const int kvh = lb & 7;
  const int h = kvh * 8 + ((lb >> 3) & 7);
  const int qt = 7 - (lb >> 6);
  const int qrow0 = qt * 256 + w * 32;
  const int qglob = qrow0 + q5;

  // permuted K row for the S^T A-operand: m = q5 -> kr = g(m)
  const int pa = q5 & 3, pp = (q5 >> 2) & 1, pb = q5 >> 3;
  const int kr = (pb >> 1) * 16 + pp * 8 + (pb & 1) * 4 + pa;
  const int kswz = (kr & 7) << 4;
  const int swz = (q5 & 7) << 4;

  // Q fragments (B-operand): col q = q5, k-slice = hi*8; 8 k-steps of 16
  short8 qf[8];
#pragma unroll
  for (int ks = 0; ks < 8; ++ks)
    qf[ks] = *(const short8*)(Qg + ((size_t)h * 2048 + qglob) * 128 + ks * 16 + hi * 8);

  f32x16 o[4] = {};
  float mrun = -3.0e38f, lrun = 0.0f;

  const int kbmax_blk = 4 * qt + 3;
  const int kbmax_w = (qrow0 + 31) >> 6;

  // stage K,V tiles: 1024 16B slots each over 512 threads (2 slots/thread).
  // K buf b at SM + b*8192 elems; V^T buf b at SM + 16384 + b*8192 elems.
  auto STAGE = [&](int b, int kb) {
#pragma unroll
    for (int i = 0; i < 2; ++i) {
      int slot = t + i * 512;                    // K
      int kv = slot >> 4, c = slot & 15;
      int csrc = c ^ (kv & 7);
      __builtin_amdgcn_global_load_lds(AS1U(Kg + ((size_t)kvh * 2048 + kb * 64 + kv) * 128 + csrc * 8),
                                       AS3U(SM + b * 8192 + slot * 8), 16, 0, 0);
    }
#pragma unroll
    for (int i = 0; i < 2; ++i) {
      int slot = t + i * 512;                    // V^T
      int d = slot >> 3, c = slot & 7;
      int csrc = c ^ (d & 7);
      __builtin_amdgcn_global_load_lds(AS1U(VtG + ((size_t)kvh * 128 + d) * 2048 + kb * 64 + csrc * 8),
                                       AS3U(SM + 16384 + b * 8192 + slot * 8), 16, 0, 0);
    }
  };

  STAGE(0, 0);
  int cur = 0;

  for (int kb = 0; kb <= kbmax_blk; ++kb) {
    asm volatile("s_waitcnt vmcnt(0)" ::: "memory");
    __syncthreads();
    if (kb < kbmax_blk) STAGE(cur ^ 1, kb + 1);

    if (kb <= kbmax_w) {
      const char* kbase = (const char*)(SM + cur * 8192);
      const char* vbase = (const char*)(SM + 16384 + cur * 8192);

      // ---- S^T = K_perm · Q^T ----
      f32x16 st0 = {}, st1 = {};
#pragma unroll
      for (int ks = 0; ks < 8; ++ks) {
        int cslot = ((ks * 2 + hi) * 16) ^ kswz;
        short8 kf0 = *(const short8*)(kbase + kr * 256 + cslot);
        short8 kf1 = *(const short8*)(kbase + (32 + kr) * 256 + cslot);
        __builtin_amdgcn_s_setprio(1);
        st0 = __builtin_amdgcn_mfma_f32_32x32x16_bf16(kf0, qf[ks], st0, 0, 0, 0);
        st1 = __builtin_amdgcn_mfma_f32_32x32x16_bf16(kf1, qf[ks], st1, 0, 0, 0);
        __builtin_amdgcn_s_setprio(0);
      }

      // ---- causal mask (diagonal tile only); st reg r holds kv = (r>>3)*16 + hi*8 + (r&7) ----
      if (kb == kbmax_w) {
#pragma unroll
        for (int r = 0; r < 16; ++r) {
          int kv0 = kb * 64 + (r >> 3) * 16 + hi * 8 + (r & 7);
          if (kv0 > qglob) st0[r] = -1.0e30f;
          if (kv0 + 32 > qglob) st1[r] = -1.0e30f;
        }
      }

      // ---- online softmax, per-lane row (defer-max THR=8) ----
      float pmax = st0[0];
#pragma unroll
      for (int r = 1; r < 16; ++r) pmax = fmaxf(pmax, st0[r]);
#pragma unroll
      for (int r = 0; r < 16; ++r) pmax = fmaxf(pmax, st1[r]);
      pmax = fmaxf(pmax, __shfl_xor(pmax, 32));
      if (!__all(pmax <= mrun + 8.0f)) {
        float mn = fmaxf(mrun, pmax);
        float sc = __expf(mrun - mn);
        mrun = mn;
        lrun *= sc;
#pragma unroll
        for (int db = 0; db < 4; ++db) o[db] *= sc;
      }
      float rs = 0.0f;
#pragma unroll
      for (int r = 0; r < 16; ++r) { st0[r] = __expf(st0[r] - mrun); rs += st0[r]; }
#pragma unroll
      for (int r = 0; r < 16; ++r) { st1[r] = __expf(st1[r] - mrun); rs += st1[r]; }
      rs += __shfl_xor(rs, 32);
      lrun += rs;

      // ---- P -> bf16 PV fragments (register order matches; no cross-lane) ----
      short8 pf[4];
      PACK8(pf[0], st0, 0);
      PACK8(pf[1], st0, 8);
      PACK8(pf[2], st1, 0);
      PACK8(pf[3], st1, 8);

      // ---- O^T += V^T · P^T ----
#pragma unroll
      for (int db = 0; db < 4; ++db) {
#pragma unroll
        for (int ks = 0; ks < 4; ++ks) {
          short8 vf = *(const short8*)(vbase + (db * 32 + q5) * 128 + ((((ks * 2 + hi) * 16)) ^ swz));
          __builtin_amdgcn_s_setprio(1);
          o[db] = __builtin_amdgcn_mfma_f32_32x32x16_bf16(vf, pf[ks], o[db], 0, 0, 0);
          __builtin_amdgcn_s_setprio(0);
        }
      }
    }
    cur ^= 1;
  }

  // ---- epilogue: normalize, transpose via LDS (per-wave 8KB of the 64KB arena) ----
  __syncthreads();
  char* tr = ((char*)SM) + w * 8192;  // [32 q][128 d] bf16, chunk-XOR swizzled by q-row
  float inv = 1.0f / lrun;
#pragma unroll
  for (int db = 0; db < 4; ++db)
#pragma unroll
    for (int r = 0; r < 16; r += 2) {
      unsigned int u;
      float lo = o[db][r] * inv, hiv = o[db][r + 1] * inv;
      asm("v_cvt_pk_bf16_f32 %0, %1, %2" : "=v"(u) : "v"(lo), "v"(hiv));
      int d = db * 32 + (r & 3) + 8 * (r >> 2) + 4 * hi;
      *(unsigned int*)(tr + q5 * 256 + ((d * 2) ^ swz)) = u;
    }
  asm volatile("s_waitcnt lgkmcnt(0)" ::: "memory");
#pragma unroll
  for (int p = 0; p < 8; ++p) {
    int row = (lane >> 3) + (p >> 1) * 8;
    int c = (lane & 7) + (p & 1) * 8;
    short8 v = *(const short8*)(tr + row * 256 + ((c * 16) ^ ((row & 7) << 4)));
    *(short8*)(Og + (size_t)(qrow0 + row) * 8192 + h * 128 + c * 8) = v;
  }
}

// -------------------- host --------------------
extern "C" void kernel_launch(void* const* d_in, const int* in_sizes, int n_in,
                              void* d_out, int out_size, void* d_ws, size_t ws_size,
                              hipStream_t stream) {
  const float* x = (const float*)d_in[0];
  const float* wq = (const float*)d_in[1];
  const float* wk = (const float*)d_in[2];
  const float* wv = (const float*)d_in[3];
  const float* wo = (const float*)d_in[4];
  const float* qw = (const float*)d_in[5];
  const float* kw = (const float*)d_in[6];
  const float* fc = (const float*)d_in[9];
  const float* fs = (const float*)d_in[10];

  char* ws = (char*)d_ws;
  ushort_t* Wb = (ushort_t*)(ws);
  ushort_t* qkv = (ushort_t*)(ws + 104857600);
  ushort_t* xb = (ushort_t*)(ws + 146800640);
  ushort_t* Qb = xb;
  ushort_t* Kb = (ushort_t*)(ws + 180355072);
  ushort_t* Vtb = (ushort_t*)(ws + 184549376);
  ushort_t* attnb = qkv;

  // all pre-GEMM f32->bf16 conversions in ONE launch (x, wq, wk, wv)
  cvt_all<<<dim3(30720), 256, 0, stream>>>(x, wq, wk, wv, xb, Wb);

  // qkv = x @ [wq;wk;wv]^T   (2048 x 10240 x 5120): 256x320 tiles -> exactly 256 blocks
  gemmQ<0, 8, 5><<<dim3(8, 32), 512, 0, stream>>>(xb, Wb, qkv, 2048, 10240, 5120);

  // convert wo (reuses Wb region; must follow gemm1)
  {
    int n8 = 5120 * 8192 / 8;
    cvt_bf16<<<dim3((n8 + 255) / 256), 256, 0, stream>>>(wo, Wb, n8);
  }

  // rmsnorm + rope + split into head-major Q/K
  normrope<<<dim3(18, 2048), 256, 0, stream>>>(qkv, qw, kw, fc, fs, Qb, Kb);

  // V transpose: [s][kvh][d] -> [kvh][d][s]
  vtrans<<<dim3(32, 8), 256, 0, stream>>>(qkv, Vtb);

  // causal flash attention: 512 blocks x 8 waves, 256 q-rows per block
  attn_fwd<<<dim3(512), 512, 0, stream>>>(Qb, Kb, Vtb, attnb);

  // out = attn @ wo^T  (2048 x 5120 x 8192), f32: 128x320 tiles -> exactly 256 blocks,
  // ring-5 single-barrier schedule
  gemmR<1, 4, 5><<<dim3(16, 16), 512, 0, stream>>>(attnb, Wb, (float*)d_out, 2048, 5120, 8192);
}